// Round 6
// baseline (93.718 us; speedup 1.0000x reference)
//
#include <hip/hip_runtime.h>

#define NH 300          // hidden units
#define BLK 256
#define RPT 4           // contiguous rows per thread

// ws layout:
//   [0, NH*16)        : float4 coef[j] = {a_j, b_j, c_j, 0.5*W32_j}
//   [NH*16, NH*16+12) : float W31prime[3]  (bias-folded linear term)

__global__ __launch_bounds__(320)
void phi2_precompute(const float* __restrict__ varphi1,   // [300,3]
                     const float* __restrict__ varphi2,   // [300]
                     const float* __restrict__ l1,        // [3]
                     const float* __restrict__ l2,        // [300]
                     const float* __restrict__ l3,        // [1]
                     float4* __restrict__ coef,
                     float* __restrict__ w31p) {
    __shared__ float red[5][3];
    int j = threadIdx.x;
    float p0 = 0.f, p1 = 0.f, p2 = 0.f;
    if (j < NH) {
        float lv2  = l2[j];
        float phi2 = varphi2[j];
        float W32 = phi2 * (lv2 - l3[0]);          // W_32[j]
        float v0 = varphi1[j*3+0], v1 = varphi1[j*3+1], v2 = varphi1[j*3+2];
        float a = v0 * (l1[0] - lv2);              // W_21[j,k]
        float b = v1 * (l1[1] - lv2);
        float c = v2 * (l1[2] - lv2);
        coef[j] = make_float4(a, b, c, 0.5f * W32);
        // W31'_k = sum_j W32_j * (0.5*W21[j,k] - varphi1[j,k])
        p0 = W32 * (0.5f * a - v0);
        p1 = W32 * (0.5f * b - v1);
        p2 = W32 * (0.5f * c - v2);
    }
    for (int off = 32; off > 0; off >>= 1) {
        p0 += __shfl_down(p0, off);
        p1 += __shfl_down(p1, off);
        p2 += __shfl_down(p2, off);
    }
    int wave = threadIdx.x >> 6;
    if ((threadIdx.x & 63) == 0) {
        red[wave][0] = p0; red[wave][1] = p1; red[wave][2] = p2;
    }
    __syncthreads();
    if (threadIdx.x == 0) {
        float s0 = 0.f, s1 = 0.f, s2 = 0.f;
        for (int w = 0; w < 5; ++w) { s0 += red[w][0]; s1 += red[w][1]; s2 += red[w][2]; }
        w31p[0] = s0; w31p[1] = s1; w31p[2] = s2;
    }
}

// No LDS. Coefficients are read with a uniform index from a const __restrict__
// pointer in divergence-free code -> hipcc scalarizes to s_load_dwordx4 (scalar
// cache, scalar pipe, parallel to VALU). Inner loop: 3 v_fma_f32 per (row, j),
// |d| folded as a VOP3 input modifier.
__global__ __launch_bounds__(BLK)
void phi2_main(const float* __restrict__ x,       // [B,2]
               const float4* __restrict__ coef,   // [300]
               const float* __restrict__ w31p,    // [3]
               float* __restrict__ y,             // [B]
               int B) {
    long t  = (long)blockIdx.x * BLK + threadIdx.x;
    long r0 = t * RPT;
    if (r0 >= B) return;

    float w0 = w31p[0], w1 = w31p[1], w2 = w31p[2];

    float x0[RPT], x1[RPT], acc[RPT];
    bool full = (r0 + RPT <= B);
    if (full) {
        // rows r0..r0+3 contiguous: two 16B loads, fully coalesced
        float4 xa = *(const float4*)(x + 2 * r0);      // rows r0, r0+1
        float4 xb = *(const float4*)(x + 2 * r0 + 4);  // rows r0+2, r0+3
        x0[0] = xa.x; x1[0] = xa.y;
        x0[1] = xa.z; x1[1] = xa.w;
        x0[2] = xb.x; x1[2] = xb.y;
        x0[3] = xb.z; x1[3] = xb.w;
    } else {
#pragma unroll
        for (int r = 0; r < RPT; ++r) {
            long row = r0 + r;
            if (row < B) { x0[r] = x[2*row]; x1[r] = x[2*row+1]; }
            else         { x0[r] = 0.f;      x1[r] = 0.f; }
        }
    }
#pragma unroll
    for (int r = 0; r < RPT; ++r)
        acc[r] = fmaf(w0, x0[r], fmaf(w1, x1[r], w2));   // folded linear part

#pragma unroll 4
    for (int j = 0; j < NH; ++j) {
        const float4 cf = coef[j];   // uniform -> s_load_dwordx4
#pragma unroll
        for (int r = 0; r < RPT; ++r) {
            float d = fmaf(cf.x, x0[r], fmaf(cf.y, x1[r], cf.z));
            acc[r] = fmaf(cf.w, fabsf(d), acc[r]);
        }
    }

    if (full) {
        *(float4*)(y + r0) = make_float4(acc[0], acc[1], acc[2], acc[3]);
    } else {
#pragma unroll
        for (int r = 0; r < RPT; ++r)
            if (r0 + r < B) y[r0 + r] = acc[r];
    }
}

extern "C" void kernel_launch(void* const* d_in, const int* in_sizes, int n_in,
                              void* d_out, int out_size, void* d_ws, size_t ws_size,
                              hipStream_t stream) {
    const float* x       = (const float*)d_in[0];
    const float* varphi1 = (const float*)d_in[1];
    const float* varphi2 = (const float*)d_in[2];
    const float* l1      = (const float*)d_in[3];
    const float* l2      = (const float*)d_in[4];
    const float* l3      = (const float*)d_in[5];

    float4* coef = (float4*)d_ws;
    float*  w31p = (float*)((char*)d_ws + NH * sizeof(float4));
    float*  y    = (float*)d_out;

    int B = in_sizes[0] / 2;

    phi2_precompute<<<1, 320, 0, stream>>>(varphi1, varphi2, l1, l2, l3, coef, w31p);

    int threads = (B + RPT - 1) / RPT;
    int grid = (threads + BLK - 1) / BLK;
    phi2_main<<<grid, BLK, 0, stream>>>(x, coef, w31p, y, B);
}

// Round 9
// 83.921 us; speedup vs baseline: 1.1167x; 1.1167x over previous
//
#include <hip/hip_runtime.h>

#define NH   300      // hidden units
#define NPAD 320      // padded coef entries (zeros beyond NH)
#define BLK  256
#define RPT  8        // contiguous rows per thread; 500000 = 8 * 62500 exactly

// ws layout:
//   [0, NPAD*16)          : float4 coef[j] = {B=b/a, C=c/a, A=s*|a|, 0}
//   [NPAD*16, NPAD*16+12) : float W31prime[3] (bias-folded linear term)

__global__ __launch_bounds__(NPAD)
void phi2_precompute(const float* __restrict__ varphi1,   // [300,3]
                     const float* __restrict__ varphi2,   // [300]
                     const float* __restrict__ l1,        // [3]
                     const float* __restrict__ l2,        // [300]
                     const float* __restrict__ l3,        // [1]
                     float4* __restrict__ coef,
                     float* __restrict__ w31p) {
    __shared__ float red[NPAD/64][3];
    int j = threadIdx.x;
    float p0 = 0.f, p1 = 0.f, p2 = 0.f;
    if (j < NH) {
        float lv2  = l2[j];
        float phi2 = varphi2[j];
        float W32  = phi2 * (lv2 - l3[0]);            // W_32[j]
        float s    = 0.5f * W32;                      // relu = (d+|d|)/2, linear half folded
        float v0 = varphi1[j*3+0], v1 = varphi1[j*3+1], v2 = varphi1[j*3+2];
        float a = v0 * (l1[0] - lv2);                 // W_21[j,:]
        float b = v1 * (l1[1] - lv2);
        float c = v2 * (l1[2] - lv2);
        // factor line by a: s*|d| = (s*|a|) * |x0 + (b/a)*x1 + (c/a)|
        float asafe = (fabsf(a) > 1e-20f) ? a : copysignf(1e-20f, a);
        coef[j] = make_float4(b / asafe, c / asafe, s * fabsf(asafe), 0.f);
        // W31'_k = sum_j W32_j * (0.5*W21[j,k] - varphi1[j,k])
        p0 = W32 * (0.5f * a - v0);
        p1 = W32 * (0.5f * b - v1);
        p2 = W32 * (0.5f * c - v2);
    } else {
        coef[j] = make_float4(0.f, 0.f, 0.f, 0.f);    // A=0 -> zero contribution
    }
    for (int off = 32; off > 0; off >>= 1) {
        p0 += __shfl_down(p0, off);
        p1 += __shfl_down(p1, off);
        p2 += __shfl_down(p2, off);
    }
    int wave = threadIdx.x >> 6;
    if ((threadIdx.x & 63) == 0) {
        red[wave][0] = p0; red[wave][1] = p1; red[wave][2] = p2;
    }
    __syncthreads();
    if (threadIdx.x == 0) {
        float s0 = 0.f, s1 = 0.f, s2 = 0.f;
        for (int w = 0; w < NPAD/64; ++w) { s0 += red[w][0]; s1 += red[w][1]; s2 += red[w][2]; }
        w31p[0] = s0; w31p[1] = s1; w31p[2] = s2;
    }
}

__device__ __forceinline__ float rl(float v, int lane) {
    return __uint_as_float(__builtin_amdgcn_readlane(__float_as_uint(v), lane));
}

// Coefficient feed via v_readlane: each wave loads 64 units' float4 with ONE
// coalesced global_load_dwordx4 (lane l holds unit chunk*64+l), then
// broadcasts via readlane (VALU). No LDS, no per-j VMEM. Every inner-loop op
// reads <=1 SGPR (legal operand form): fma(B,x1,x0) ; +C ; fma(A,|t|,acc).
__global__ __launch_bounds__(BLK)
void phi2_main(const float* __restrict__ x,       // [B,2]
               const float4* __restrict__ coef,   // [NPAD]
               const float* __restrict__ w31p,    // [3]
               float* __restrict__ y,             // [B]
               int nthreads) {
    int t    = blockIdx.x * BLK + threadIdx.x;
    int lane = threadIdx.x & 63;
    bool active = (t < nthreads);
    int tc = active ? t : (nthreads - 1);   // keep inactive lanes converged (readlane needs whole wave)

    const float4* xq = (const float4*)x + (size_t)tc * 4;   // 8 rows = 4 float4
    float4 xa = xq[0], xb = xq[1], xc = xq[2], xd = xq[3];
    float X0[RPT] = {xa.x, xa.z, xb.x, xb.z, xc.x, xc.z, xd.x, xd.z};
    float X1[RPT] = {xa.y, xa.w, xb.y, xb.w, xc.y, xc.w, xd.y, xd.w};

    float w0 = w31p[0], w1 = w31p[1], w2 = w31p[2];
    float acc[RPT];
#pragma unroll
    for (int r = 0; r < RPT; ++r)
        acc[r] = fmaf(w0, X0[r], fmaf(w1, X1[r], w2));   // folded linear part

    float4 cur = coef[lane];                 // chunk 0
#pragma unroll
    for (int ch = 0; ch < 4; ++ch) {
        float4 nxt = coef[(ch + 1) * 64 + lane];   // prefetch; hidden under ~3400 cyc of VALU
#pragma unroll 4
        for (int jj = 0; jj < 64; ++jj) {
            float Bv = rl(cur.x, jj);
            float Cv = rl(cur.y, jj);
            float Av = rl(cur.z, jj);
#pragma unroll
            for (int r = 0; r < RPT; ++r) {
                float tt = fmaf(Bv, X1[r], X0[r]) + Cv;
                acc[r] = fmaf(Av, fabsf(tt), acc[r]);    // |t| = free VOP3 modifier
            }
        }
        cur = nxt;
    }
    // tail chunk: units 256..299 (44 live; lanes 44..63 of cur hold zeros)
#pragma unroll 4
    for (int jj = 0; jj < 44; ++jj) {
        float Bv = rl(cur.x, jj);
        float Cv = rl(cur.y, jj);
        float Av = rl(cur.z, jj);
#pragma unroll
        for (int r = 0; r < RPT; ++r) {
            float tt = fmaf(Bv, X1[r], X0[r]) + Cv;
            acc[r] = fmaf(Av, fabsf(tt), acc[r]);
        }
    }

    if (active) {
        float4* yq = (float4*)y + (size_t)t * 2;
        yq[0] = make_float4(acc[0], acc[1], acc[2], acc[3]);
        yq[1] = make_float4(acc[4], acc[5], acc[6], acc[7]);
    }
}

extern "C" void kernel_launch(void* const* d_in, const int* in_sizes, int n_in,
                              void* d_out, int out_size, void* d_ws, size_t ws_size,
                              hipStream_t stream) {
    const float* x       = (const float*)d_in[0];
    const float* varphi1 = (const float*)d_in[1];
    const float* varphi2 = (const float*)d_in[2];
    const float* l1      = (const float*)d_in[3];
    const float* l2      = (const float*)d_in[4];
    const float* l3      = (const float*)d_in[5];

    float4* coef = (float4*)d_ws;
    float*  w31p = (float*)((char*)d_ws + NPAD * sizeof(float4));
    float*  y    = (float*)d_out;

    int B = in_sizes[0] / 2;

    phi2_precompute<<<1, NPAD, 0, stream>>>(varphi1, varphi2, l1, l2, l3, coef, w31p);

    int nthreads = (B + RPT - 1) / RPT;               // 62500
    int grid = (nthreads + BLK - 1) / BLK;            // 245
    phi2_main<<<grid, BLK, 0, stream>>>(x, coef, w31p, y, nthreads);
}

// Round 10
// 83.138 us; speedup vs baseline: 1.1273x; 1.0094x over previous
//
#include <hip/hip_runtime.h>

#define NH  300     // hidden units
#define BLK 64      // one wave per block: no barriers, no LDS
#define RPT 8       // contiguous rows per thread; 500000 = 8 * 62500

__device__ __forceinline__ float rl(float v, int lane) {
    return __uint_as_float(__builtin_amdgcn_readlane(__float_as_uint(v), lane));
}

// Fully fused: each wave (a) computes all 300 hidden-unit coefficients in
// registers (lane l owns units ch*64+l, ch=0..4), (b) wave-reduces the folded
// linear term W31', (c) runs the readlane-fed VALU inner loop over its 8 rows.
// relu(d) = (d+|d|)/2: linear half folded into W31'; |.| half factored by 'a'
// so every inner-loop op reads <=1 SGPR: fma(B,x1,x0); +C; fma(A,|t|,acc).
__global__ __launch_bounds__(BLK)
void phi2_fused(const float* __restrict__ x,        // [B,2]
                const float* __restrict__ varphi1,  // [300,3]
                const float* __restrict__ varphi2,  // [300]
                const float* __restrict__ l1,       // [3]
                const float* __restrict__ l2,       // [300]
                const float* __restrict__ l3,       // [1]
                float* __restrict__ y,              // [B]
                int nthreads) {
    int lane = threadIdx.x;                  // 0..63
    int t    = blockIdx.x * BLK + lane;
    bool active = (t < nthreads);
    int tc = active ? t : (nthreads - 1);    // keep lanes converged for readlane

    // Issue x loads FIRST: HBM latency hides under the coefficient prologue.
    const float4* xq = (const float4*)x + (size_t)tc * 4;   // 8 rows = 4 float4
    float4 xa = xq[0], xb = xq[1], xc = xq[2], xd = xq[3];

    // ---- per-wave coefficient prologue (redundant per wave, ~0.2 us) ----
    float l10 = l1[0], l11 = l1[1], l12 = l1[2], l30 = l3[0];
    float Bc[5], Cc[5], Ac[5];
    float p0 = 0.f, p1 = 0.f, p2 = 0.f;
#pragma unroll
    for (int ch = 0; ch < 5; ++ch) {
        int j = ch * 64 + lane;
        bool live = (j < NH);
        int jc = live ? j : (NH - 1);        // clamp reads; contribution zeroed
        float lv2  = l2[jc];
        float phi2 = varphi2[jc];
        float W32  = live ? phi2 * (lv2 - l30) : 0.f;   // W_32[j]
        float s    = 0.5f * W32;
        float v0 = varphi1[jc*3+0], v1 = varphi1[jc*3+1], v2 = varphi1[jc*3+2];
        float a = v0 * (l10 - lv2);          // W_21[j,:]
        float b = v1 * (l11 - lv2);
        float c = v2 * (l12 - lv2);
        // s*|d| = (s*|a|) * |x0 + (b/a)x1 + (c/a)|
        float asafe = (fabsf(a) > 1e-20f) ? a : copysignf(1e-20f, a);
        float inva  = 1.0f / asafe;
        Bc[ch] = b * inva;
        Cc[ch] = c * inva;
        Ac[ch] = s * fabsf(asafe);
        // W31'_k partial: sum_j W32_j*(0.5*W21[j,k] - varphi1[j,k])  (dead: W32=0)
        p0 = fmaf(W32, 0.5f * a - v0, p0);
        p1 = fmaf(W32, 0.5f * b - v1, p1);
        p2 = fmaf(W32, 0.5f * c - v2, p2);
    }
    // wave-reduce W31' and broadcast
    for (int off = 32; off > 0; off >>= 1) {
        p0 += __shfl_down(p0, off);
        p1 += __shfl_down(p1, off);
        p2 += __shfl_down(p2, off);
    }
    p0 = rl(p0, 0); p1 = rl(p1, 0); p2 = rl(p2, 0);

    // ---- main loop over 8 rows ----
    float X0[RPT] = {xa.x, xa.z, xb.x, xb.z, xc.x, xc.z, xd.x, xd.z};
    float X1[RPT] = {xa.y, xa.w, xb.y, xb.w, xc.y, xc.w, xd.y, xd.w};
    float acc[RPT];
#pragma unroll
    for (int r = 0; r < RPT; ++r)
        acc[r] = fmaf(p0, X0[r], fmaf(p1, X1[r], p2));   // folded linear part

#pragma unroll
    for (int ch = 0; ch < 5; ++ch) {
        const int cnt = (ch == 4) ? (NH - 256) : 64;     // 44 live units in last chunk
#pragma unroll 4
        for (int jj = 0; jj < cnt; ++jj) {
            float Bs = rl(Bc[ch], jj);
            float Cs = rl(Cc[ch], jj);
            float As = rl(Ac[ch], jj);
#pragma unroll
            for (int r = 0; r < RPT; ++r) {
                float tt = fmaf(Bs, X1[r], X0[r]) + Cs;
                acc[r] = fmaf(As, fabsf(tt), acc[r]);    // |t| = free VOP3 modifier
            }
        }
    }

    if (active) {
        float4* yq = (float4*)y + (size_t)t * 2;
        yq[0] = make_float4(acc[0], acc[1], acc[2], acc[3]);
        yq[1] = make_float4(acc[4], acc[5], acc[6], acc[7]);
    }
}

extern "C" void kernel_launch(void* const* d_in, const int* in_sizes, int n_in,
                              void* d_out, int out_size, void* d_ws, size_t ws_size,
                              hipStream_t stream) {
    const float* x       = (const float*)d_in[0];
    const float* varphi1 = (const float*)d_in[1];
    const float* varphi2 = (const float*)d_in[2];
    const float* l1      = (const float*)d_in[3];
    const float* l2      = (const float*)d_in[4];
    const float* l3      = (const float*)d_in[5];
    float*       y       = (float*)d_out;

    int B = in_sizes[0] / 2;
    int nthreads = (B + RPT - 1) / RPT;        // 62500
    int grid = (nthreads + BLK - 1) / BLK;     // 977

    phi2_fused<<<grid, BLK, 0, stream>>>(x, varphi1, varphi2, l1, l2, l3, y, nthreads);
}